// Round 5
// baseline (3192.283 us; speedup 1.0000x reference)
//
#include <hip/hip_runtime.h>
#include <hip/hip_bf16.h>
#include <math.h>

#define NN 16384
#define DD 512
#define KSEL 10
#define MCAND 16   // filter keeps top-16 per column-split
#define NSPLIT 4   // column splits for k_sim_topk
#define RESCORE 16 // fp64-rescored candidates per row (top-16 of 64 by filter value)

typedef __bf16 bf16x8 __attribute__((ext_vector_type(8)));
typedef float  f32x4  __attribute__((ext_vector_type(4)));

#define GLOAD_LDS16(gsrc, ldst) \
    __builtin_amdgcn_global_load_lds( \
        (const __attribute__((address_space(1))) void*)(gsrc), \
        (__attribute__((address_space(3))) void*)(ldst), 16, 0, 0)

// ---------------- K1: t = tanh(3 * (emb[idx] @ W^T + b)); also emit bf16 copy ----------------
__global__ __launch_bounds__(256) void k_transform(
    const int* __restrict__ idx, const float* __restrict__ emb,
    const float* __restrict__ W, const float* __restrict__ bias,
    float* __restrict__ t_out, unsigned short* __restrict__ tb_out)
{
    __shared__ float As[32][68];   // [k][m]
    __shared__ float Bs[32][68];   // [k][n]
    const int tid = threadIdx.x;
    const int tx = tid & 15, ty = tid >> 4;
    const int m0 = (blockIdx.x >> 3) << 6;
    const int n0 = (blockIdx.x & 7) << 6;

    float acc[4][4] = {};

    const int f0 = tid, f1 = tid + 256;
    const int r0 = f0 >> 3, c0_ = f0 & 7;
    const int r1 = f1 >> 3, c1_ = f1 & 7;
    const int ga0 = idx[m0 + r0];
    const int ga1 = idx[m0 + r1];

    for (int kc = 0; kc < DD; kc += 32) {
        const float4 a0 = *(const float4*)&emb[(size_t)ga0 * DD + kc + (c0_ << 2)];
        const float4 a1 = *(const float4*)&emb[(size_t)ga1 * DD + kc + (c1_ << 2)];
        const float4 b0 = *(const float4*)&W[(size_t)(n0 + r0) * DD + kc + (c0_ << 2)];
        const float4 b1 = *(const float4*)&W[(size_t)(n0 + r1) * DD + kc + (c1_ << 2)];
        As[(c0_<<2)+0][r0] = a0.x; As[(c0_<<2)+1][r0] = a0.y;
        As[(c0_<<2)+2][r0] = a0.z; As[(c0_<<2)+3][r0] = a0.w;
        As[(c1_<<2)+0][r1] = a1.x; As[(c1_<<2)+1][r1] = a1.y;
        As[(c1_<<2)+2][r1] = a1.z; As[(c1_<<2)+3][r1] = a1.w;
        Bs[(c0_<<2)+0][r0] = b0.x; Bs[(c0_<<2)+1][r0] = b0.y;
        Bs[(c0_<<2)+2][r0] = b0.z; Bs[(c0_<<2)+3][r0] = b0.w;
        Bs[(c1_<<2)+0][r1] = b1.x; Bs[(c1_<<2)+1][r1] = b1.y;
        Bs[(c1_<<2)+2][r1] = b1.z; Bs[(c1_<<2)+3][r1] = b1.w;
        __syncthreads();
        #pragma unroll
        for (int k = 0; k < 32; ++k) {
            const float4 a = *(const float4*)&As[k][ty << 2];
            const float4 b = *(const float4*)&Bs[k][tx << 2];
            const float av[4] = {a.x, a.y, a.z, a.w};
            const float bv[4] = {b.x, b.y, b.z, b.w};
            #pragma unroll
            for (int i = 0; i < 4; ++i)
                #pragma unroll
                for (int j = 0; j < 4; ++j)
                    acc[i][j] = fmaf(av[i], bv[j], acc[i][j]);
        }
        __syncthreads();
    }

    #pragma unroll
    for (int i = 0; i < 4; ++i) {
        const int m = m0 + (ty << 2) + i;
        float o[4];
        union { __hip_bfloat16 h[4]; ushort4 u; } cc;
        #pragma unroll
        for (int j = 0; j < 4; ++j) {
            const int n = n0 + (tx << 2) + j;
            o[j] = tanhf(3.0f * (acc[i][j] + bias[n]));
            cc.h[j] = __float2bfloat16(o[j]);
        }
        *(float4*)&t_out[(size_t)m * DD + n0 + (tx << 2)] =
            make_float4(o[0], o[1], o[2], o[3]);
        *(ushort4*)&tb_out[(size_t)m * DD + n0 + (tx << 2)] = cc.u;
    }
}

// ------------- K2: bf16 MFMA sim filter, 2-phase pipelined staging -------------
// 128x128 tile/block, 4 waves (2x2), LDS A/B double-buffered (linear dest for
// global_load_lds; XOR-swizzled source + XOR-swizzled ds_read, rule #21).
// Drain: 4 rounds of 32 cols, cap 32 == round width (flood-safe); cv/ci alias
// the B buffers (free during drain; no cross-tile prefetch).
__global__ __launch_bounds__(256) void k_sim_topk(
    const unsigned short* __restrict__ tb,
    float* __restrict__ pv, unsigned short* __restrict__ pi)
{
    // LDS map (78848 B total, 2 blocks/CU):
    //   A0 @0, A1 @16384, B0 @32768, B1 @49152 (16 KB each)
    //   topv @65536 [128][16] f32, topi @73728 [128][16] u16
    //   thresh @77824 [128] f32, cnt @78336 [128] int
    //   cv [128][32] f32 aliases @32768 (B0), ci [128][32] u16 aliases @49152 (B1)
    __shared__ __align__(16) char SM[78848];
    unsigned short* Ab0 = (unsigned short*)(SM);
    unsigned short* Ab1 = (unsigned short*)(SM + 16384);
    unsigned short* Bb0 = (unsigned short*)(SM + 32768);
    unsigned short* Bb1 = (unsigned short*)(SM + 49152);
    float*          topv   = (float*)(SM + 65536);
    unsigned short* topi   = (unsigned short*)(SM + 73728);
    float*          thresh = (float*)(SM + 77824);
    int*            cnt    = (int*)(SM + 78336);
    float*          cv     = (float*)(SM + 32768);
    unsigned short* ci     = (unsigned short*)(SM + 49152);

    const int tid  = threadIdx.x;
    const int wave = tid >> 6;
    const int lane = tid & 63;
    const int wr   = wave >> 1;
    const int wc   = wave & 1;

    // XCD-aware decode: xcd = bid&7 (round-robin assumption, perf-only).
    // s = (bid>>1)&3 -> split s pinned to XCD pair {2s,2s+1}; B-panel (4MB) L2-resident.
    const int bid  = blockIdx.x;
    const int s    = (bid >> 1) & 3;
    const int mblk = ((bid & 1) << 6) | (bid >> 3);   // 0..127, bijective over 512 blocks
    const int m0   = mblk << 7;
    const int c_begin = s * (NN / NSPLIT);

    if (tid < 128) {
        thresh[tid] = -1e30f;
        cnt[tid] = 0;
        #pragma unroll
        for (int j = 0; j < MCAND; ++j) { topv[tid*MCAND + j] = -1e30f; topi[tid*MCAND + j] = 0xFFFFu; }
    }
    __syncthreads();

    const int lr8 = lane >> 3;                 // row within 8-row staging group
    const int scx = ((lane & 7) ^ lr8) << 4;   // pre-swizzled byte offset (involution)
    const char* tbb = (const char*)tb;

    for (int ct = 0; ct < (NN / NSPLIT) / 128; ++ct) {
        const int c0 = c_begin + (ct << 7);
        f32x4 acc[4][4] = {};

        // prologue: stage K-step 0 into buf0
        {
            unsigned short* Ad = Ab0; unsigned short* Bd = Bb0;
            #pragma unroll
            for (int i = 0; i < 4; ++i) {
                const int ai = (wave << 2) + i;
                GLOAD_LDS16(tbb + (size_t)(m0 + (ai << 3) + lr8) * 1024 + 0 + scx,
                            (char*)Ad + (ai << 10));
                GLOAD_LDS16(tbb + (size_t)(c0 + (ai << 3) + lr8) * 1024 + 0 + scx,
                            (char*)Bd + (ai << 10));
            }
        }
        __syncthreads();

        for (int kc8 = 0; kc8 < 8; ++kc8) {
            const int par = kc8 & 1;
            // issue next K-step's staging first (overlaps with compute below)
            if (kc8 < 7) {
                const size_t kb = (size_t)((kc8 + 1) << 7);   // *64 k * 2B
                unsigned short* Ad = par ? Ab0 : Ab1;
                unsigned short* Bd = par ? Bb0 : Bb1;
                #pragma unroll
                for (int i = 0; i < 4; ++i) {
                    const int ai = (wave << 2) + i;
                    GLOAD_LDS16(tbb + (size_t)(m0 + (ai << 3) + lr8) * 1024 + kb + scx,
                                (char*)Ad + (ai << 10));
                    GLOAD_LDS16(tbb + (size_t)(c0 + (ai << 3) + lr8) * 1024 + kb + scx,
                                (char*)Bd + (ai << 10));
                }
            }
            // compute current K-step from buf[par]
            const unsigned short* Ac = par ? Ab1 : Ab0;
            const unsigned short* Bc = par ? Bb1 : Bb0;
            #pragma unroll
            for (int ks = 0; ks < 2; ++ks) {
                bf16x8 af[4], bf[4];
                #pragma unroll
                for (int m = 0; m < 4; ++m) {
                    const int row = (wr << 6) + (m << 4) + (lane & 15);
                    const int corig = (ks << 2) + (lane >> 4);
                    af[m] = *(const bf16x8*)((const char*)Ac +
                            (row << 7) + ((corig ^ (row & 7)) << 4));
                }
                #pragma unroll
                for (int n = 0; n < 4; ++n) {
                    const int row = (wc << 6) + (n << 4) + (lane & 15);
                    const int corig = (ks << 2) + (lane >> 4);
                    bf[n] = *(const bf16x8*)((const char*)Bc +
                            (row << 7) + ((corig ^ (row & 7)) << 4));
                }
                #pragma unroll
                for (int m = 0; m < 4; ++m)
                    #pragma unroll
                    for (int n = 0; n < 4; ++n)
                        acc[m][n] = __builtin_amdgcn_mfma_f32_16x16x32_bf16(
                            af[m], bf[n], acc[m][n], 0, 0, 0);
            }
            __syncthreads();   // drains vmcnt (next buf staged) + lgkm; all waves done reading
        }

        // ---- drain: 4 rounds of 32 cols; cv/ci alias B buffers (no loads pending) ----
        #pragma unroll
        for (int rnd = 0; rnd < 4; ++rnd) {
            const int wcr = rnd >> 1;
            const int nf0 = (rnd & 1) << 1;
            if (wc == wcr) {
                #pragma unroll
                for (int m = 0; m < 4; ++m) {
                    #pragma unroll
                    for (int nn = 0; nn < 2; ++nn) {
                        #pragma unroll
                        for (int j = 0; j < 4; ++j) {
                            const int row = (wr << 6) + (m << 4) + ((lane >> 4) << 2) + j;
                            const float v = acc[m][nf0 + nn][j];
                            if (v >= thresh[row]) {   // cap 32 == round width: always safe
                                const int p = atomicAdd(&cnt[row], 1);
                                cv[(row << 5) + p] = v;
                                ci[(row << 5) + p] =
                                    (unsigned short)(c0 + (wcr << 6) + ((nf0 + nn) << 4) + (lane & 15));
                            }
                        }
                    }
                }
            }
            __syncthreads();
            if (tid < 128) {
                const int r = tid;
                const int n_ = cnt[r];
                float* tv = &topv[r * MCAND];
                unsigned short* ti = &topi[r * MCAND];
                for (int q = 0; q < n_; ++q) {
                    const float v = cv[(r << 5) + q];
                    const unsigned short c = ci[(r << 5) + q];
                    if (v > tv[MCAND-1] || (v == tv[MCAND-1] && c < ti[MCAND-1])) {
                        int p = MCAND - 1;
                        while (p > 0 && (v > tv[p-1] || (v == tv[p-1] && c < ti[p-1]))) {
                            tv[p] = tv[p-1]; ti[p] = ti[p-1]; --p;
                        }
                        tv[p] = v; ti[p] = c;
                    }
                }
                cnt[r] = 0;
                thresh[r] = tv[MCAND-1];
            }
            __syncthreads();
        }
    }

    if (tid < 128) {
        const size_t base = (((size_t)s * 128 + mblk) * 128 + tid) * MCAND;
        #pragma unroll
        for (int j = 0; j < MCAND; ++j) {
            pv[base + j] = topv[tid * MCAND + j];
            pi[base + j] = topi[tid * MCAND + j];
        }
    }
}

// ------------- K3: wave bitonic top-16-of-64 by filter value, fp64 rescore, scatter -------------
__global__ __launch_bounds__(256) void k_rescore(
    const float* __restrict__ t, const float* __restrict__ pv,
    const unsigned short* __restrict__ pi, float* __restrict__ out)
{
    const int wave = threadIdx.x >> 6;
    const int lane = threadIdx.x & 63;
    const int r = blockIdx.x * 4 + wave;
    const int mblk = r >> 7, local = r & 127;

    // lane q holds candidate (split q>>4, slot q&15)
    const int sp = lane >> 4, slot = lane & 15;
    const size_t cbase = (((size_t)sp * 128 + mblk) * 128 + local) * MCAND;
    const float v = pv[cbase + slot];
    const unsigned int idxc = pi[cbase + slot];
    // monotone key: v desc, idx asc. empty slots (v=-1e30, idx=0xFFFF) sort last.
    const unsigned int u = __float_as_uint(v);
    const unsigned int mkey = (u & 0x80000000u) ? ~u : (u | 0x80000000u);
    unsigned long long key = ((unsigned long long)mkey << 16) |
                             (unsigned long long)((~idxc) & 0xFFFFu);

    // 64-lane bitonic sort, descending
    #pragma unroll
    for (int k = 2; k <= 64; k <<= 1) {
        #pragma unroll
        for (int j = k >> 1; j > 0; j >>= 1) {
            const unsigned long long other = __shfl_xor(key, j, 64);
            const bool lower = (lane & j) == 0;
            const bool ascBlock = (lane & k) == 0;
            const bool takeMax = (lower == ascBlock);
            const bool mineBigger = key > other;
            key = (takeMax == mineBigger) ? key : other;
        }
    }
    const int cid = (int)((~(unsigned int)key) & 0xFFFFu);  // lanes 0..15: top-16 cand columns

    const float4 a0 = *(const float4*)&t[(size_t)r * DD + lane * 8];
    const float4 a1 = *(const float4*)&t[(size_t)r * DD + lane * 8 + 4];

    double bestv[KSEL];
    int    besti[KSEL];
    #pragma unroll
    for (int j = 0; j < KSEL; ++j) { bestv[j] = -1e300; besti[j] = 0x7fffffff; }

    for (int q = 0; q < RESCORE; ++q) {
        const int c = __shfl(cid, q, 64);
        const float4 v0 = *(const float4*)&t[(size_t)c * DD + lane * 8];
        const float4 v1 = *(const float4*)&t[(size_t)c * DD + lane * 8 + 4];
        double sdot = 0.0;
        sdot += (double)a0.x * (double)v0.x;
        sdot += (double)a0.y * (double)v0.y;
        sdot += (double)a0.z * (double)v0.z;
        sdot += (double)a0.w * (double)v0.w;
        sdot += (double)a1.x * (double)v1.x;
        sdot += (double)a1.y * (double)v1.y;
        sdot += (double)a1.z * (double)v1.z;
        sdot += (double)a1.w * (double)v1.w;
        #pragma unroll
        for (int off = 32; off > 0; off >>= 1)
            sdot += __shfl_down(sdot, off, 64);
        if (lane == 0) {
            if (sdot > bestv[KSEL-1] || (sdot == bestv[KSEL-1] && c < besti[KSEL-1])) {
                int p = KSEL - 1;
                while (p > 0 && (sdot > bestv[p-1] ||
                                 (sdot == bestv[p-1] && c < besti[p-1]))) {
                    bestv[p] = bestv[p-1]; besti[p] = besti[p-1]; --p;
                }
                bestv[p] = sdot; besti[p] = c;
            }
        }
    }

    if (lane == 0) {
        #pragma unroll
        for (int j = 0; j < KSEL; ++j)
            out[(size_t)besti[j] * NN + r] = 1.0f;
    }
}

extern "C" void kernel_launch(void* const* d_in, const int* in_sizes, int n_in,
                              void* d_out, int out_size, void* d_ws, size_t ws_size,
                              hipStream_t stream) {
    const int*   idx  = (const int*)d_in[0];
    const float* emb  = (const float*)d_in[1];
    const float* linw = (const float*)d_in[2];
    const float* linb = (const float*)d_in[3];
    float* out = (float*)d_out;

    // ws: t f32 32MB @0; tb bf16 16MB @32M; pv f32 4MB @48M; pi u16 2MB @52M
    float*          t  = (float*)d_ws;
    unsigned short* tb = (unsigned short*)((char*)d_ws + (size_t)32 * 1024 * 1024);
    float*          pv = (float*)((char*)d_ws + (size_t)48 * 1024 * 1024);
    unsigned short* pi = (unsigned short*)((char*)d_ws + (size_t)52 * 1024 * 1024);

    (void)hipMemsetAsync(d_out, 0, (size_t)NN * (size_t)NN * sizeof(float), stream);

    k_transform<<<dim3(256 * 8), dim3(256), 0, stream>>>(idx, emb, linw, linb, t, tb);
    k_sim_topk<<<dim3((NN / 128) * NSPLIT), dim3(256), 0, stream>>>(tb, pv, pi);
    k_rescore<<<dim3(NN / 4), dim3(256), 0, stream>>>(t, pv, pi, out);
}

// Round 6
// 2338.425 us; speedup vs baseline: 1.3651x; 1.3651x over previous
//
#include <hip/hip_runtime.h>
#include <hip/hip_bf16.h>
#include <math.h>

#define NN 16384
#define DD 512
#define KSEL 10
#define MCAND 16   // filter keeps top-16 per column-split
#define NSPLIT 4   // column splits for k_sim_topk
#define RESCORE 16 // fp64-rescored candidates per row (top-16 of 64 by filter value)

typedef __bf16 bf16x8 __attribute__((ext_vector_type(8)));
typedef float  f32x4  __attribute__((ext_vector_type(4)));

#define GLOAD_LDS16(gsrc, ldst) \
    __builtin_amdgcn_global_load_lds( \
        (const __attribute__((address_space(1))) void*)(gsrc), \
        (__attribute__((address_space(3))) void*)(ldst), 16, 0, 0)

// ---------------- K1: t = tanh(3 * (emb[idx] @ W^T + b)); also emit bf16 copy ----------------
__global__ __launch_bounds__(256) void k_transform(
    const int* __restrict__ idx, const float* __restrict__ emb,
    const float* __restrict__ W, const float* __restrict__ bias,
    float* __restrict__ t_out, unsigned short* __restrict__ tb_out)
{
    __shared__ float As[32][68];   // [k][m]
    __shared__ float Bs[32][68];   // [k][n]
    const int tid = threadIdx.x;
    const int tx = tid & 15, ty = tid >> 4;
    const int m0 = (blockIdx.x >> 3) << 6;
    const int n0 = (blockIdx.x & 7) << 6;

    float acc[4][4] = {};

    const int f0 = tid, f1 = tid + 256;
    const int r0 = f0 >> 3, c0_ = f0 & 7;
    const int r1 = f1 >> 3, c1_ = f1 & 7;
    const int ga0 = idx[m0 + r0];
    const int ga1 = idx[m0 + r1];

    for (int kc = 0; kc < DD; kc += 32) {
        const float4 a0 = *(const float4*)&emb[(size_t)ga0 * DD + kc + (c0_ << 2)];
        const float4 a1 = *(const float4*)&emb[(size_t)ga1 * DD + kc + (c1_ << 2)];
        const float4 b0 = *(const float4*)&W[(size_t)(n0 + r0) * DD + kc + (c0_ << 2)];
        const float4 b1 = *(const float4*)&W[(size_t)(n0 + r1) * DD + kc + (c1_ << 2)];
        As[(c0_<<2)+0][r0] = a0.x; As[(c0_<<2)+1][r0] = a0.y;
        As[(c0_<<2)+2][r0] = a0.z; As[(c0_<<2)+3][r0] = a0.w;
        As[(c1_<<2)+0][r1] = a1.x; As[(c1_<<2)+1][r1] = a1.y;
        As[(c1_<<2)+2][r1] = a1.z; As[(c1_<<2)+3][r1] = a1.w;
        Bs[(c0_<<2)+0][r0] = b0.x; Bs[(c0_<<2)+1][r0] = b0.y;
        Bs[(c0_<<2)+2][r0] = b0.z; Bs[(c0_<<2)+3][r0] = b0.w;
        Bs[(c1_<<2)+0][r1] = b1.x; Bs[(c1_<<2)+1][r1] = b1.y;
        Bs[(c1_<<2)+2][r1] = b1.z; Bs[(c1_<<2)+3][r1] = b1.w;
        __syncthreads();
        #pragma unroll
        for (int k = 0; k < 32; ++k) {
            const float4 a = *(const float4*)&As[k][ty << 2];
            const float4 b = *(const float4*)&Bs[k][tx << 2];
            const float av[4] = {a.x, a.y, a.z, a.w};
            const float bv[4] = {b.x, b.y, b.z, b.w};
            #pragma unroll
            for (int i = 0; i < 4; ++i)
                #pragma unroll
                for (int j = 0; j < 4; ++j)
                    acc[i][j] = fmaf(av[i], bv[j], acc[i][j]);
        }
        __syncthreads();
    }

    #pragma unroll
    for (int i = 0; i < 4; ++i) {
        const int m = m0 + (ty << 2) + i;
        float o[4];
        union { __hip_bfloat16 h[4]; ushort4 u; } cc;
        #pragma unroll
        for (int j = 0; j < 4; ++j) {
            const int n = n0 + (tx << 2) + j;
            o[j] = tanhf(3.0f * (acc[i][j] + bias[n]));
            cc.h[j] = __float2bfloat16(o[j]);
        }
        *(float4*)&t_out[(size_t)m * DD + n0 + (tx << 2)] =
            make_float4(o[0], o[1], o[2], o[3]);
        *(ushort4*)&tb_out[(size_t)m * DD + n0 + (tx << 2)] = cc.u;
    }
}

// ------------- K2: bf16 MFMA sim filter — 256x128 tile, 8 waves, BK=64 double-buffered -------------
// 512 threads, waves 4x2 (each 64x64 via 4x4 frags of 16x16x32 bf16).
// LDS (122 KB, 1 block/CU): A db 2x32KB, B db 2x16KB, aux 26KB; cv/ci alias A bufs in drain.
// global_load_lds: linear LDS dest + pre-swizzled source col; ds_read applies same XOR (rule #21).
__global__ __launch_bounds__(512) void k_sim_topk(
    const unsigned short* __restrict__ tb,
    float* __restrict__ pv, unsigned short* __restrict__ pi)
{
    // LDS map: A0@0 A1@32768 (32KB each), B0@65536 B1@81920 (16KB each),
    // topv@98304 [256][16]f32, topi@114688 [256][16]u16,
    // thresh@122880 [256]f32, cnt@123904 [256]i32. Total 124928.
    // drain aliases: cv[256][32]f32 @0 (A0), ci[256][32]u16 @32768 (A1).
    __shared__ __align__(16) char SM[124928];
    unsigned short* Ab0 = (unsigned short*)(SM);
    unsigned short* Ab1 = (unsigned short*)(SM + 32768);
    unsigned short* Bb0 = (unsigned short*)(SM + 65536);
    unsigned short* Bb1 = (unsigned short*)(SM + 81920);
    float*          topv   = (float*)(SM + 98304);
    unsigned short* topi   = (unsigned short*)(SM + 114688);
    float*          thresh = (float*)(SM + 122880);
    int*            cnt    = (int*)(SM + 123904);
    float*          cv     = (float*)(SM);            // alias A0
    unsigned short* ci     = (unsigned short*)(SM + 32768);  // alias A1

    const int tid  = threadIdx.x;
    const int wave = tid >> 6;     // 0..7
    const int lane = tid & 63;
    const int wr   = wave >> 1;    // 0..3 -> rows wr*64
    const int wc   = wave & 1;     // 0..1 -> cols wc*64

    // XCD-aware decode (perf-only): xcd = bid&7; split s = xcd>>1 pinned to XCD pair;
    // mblk = (bid&1)<<5 | bid>>3 is bijective over 256 blocks.
    const int bid  = blockIdx.x;
    const int s    = (bid & 7) >> 1;                 // 0..3
    const int mblk = ((bid & 1) << 5) | (bid >> 3);  // 0..63
    const int m0   = mblk << 8;                      // 256-row panel
    const int c_begin = s * (NN / NSPLIT);

    if (tid < 256) {
        thresh[tid] = -1e30f;
        cnt[tid] = 0;
        #pragma unroll
        for (int j = 0; j < MCAND; ++j) { topv[tid*MCAND + j] = -1e30f; topi[tid*MCAND + j] = 0xFFFFu; }
    }
    __syncthreads();

    const int lr8 = lane >> 3;                 // row within 8-row staging group
    const int scx = ((lane & 7) ^ lr8) << 4;   // pre-swizzled byte offset (involution)
    const char* tbb = (const char*)tb;

#define STAGE_STEP(Ad, Bd, kb) do { \
    _Pragma("unroll") \
    for (int i_ = 0; i_ < 4; ++i_) { \
        const int ai_ = (wave << 2) + i_; \
        GLOAD_LDS16(tbb + (size_t)(m0 + (ai_ << 3) + lr8) * 1024 + (kb) + scx, \
                    (char*)(Ad) + (ai_ << 10)); \
    } \
    _Pragma("unroll") \
    for (int i_ = 0; i_ < 2; ++i_) { \
        const int bi_ = (wave << 1) + i_; \
        GLOAD_LDS16(tbb + (size_t)(c0 + (bi_ << 3) + lr8) * 1024 + (kb) + scx, \
                    (char*)(Bd) + (bi_ << 10)); \
    } \
} while (0)

    for (int ct = 0; ct < (NN / NSPLIT) / 128; ++ct) {
        const int c0 = c_begin + (ct << 7);
        f32x4 acc[4][4] = {};

        // prologue: stage K-step 0 into buf0
        STAGE_STEP(Ab0, Bb0, 0);
        __syncthreads();

        for (int kc8 = 0; kc8 < 8; ++kc8) {
            const int par = kc8 & 1;
            // issue next K-step's staging first (overlaps with compute below)
            if (kc8 < 7) {
                const size_t kb = (size_t)((kc8 + 1) << 7);   // *64 k * 2B
                if (par == 0) { STAGE_STEP(Ab1, Bb1, kb); }
                else          { STAGE_STEP(Ab0, Bb0, kb); }
            }
            // compute current K-step from buf[par]
            const unsigned short* Ac = par ? Ab1 : Ab0;
            const unsigned short* Bc = par ? Bb1 : Bb0;
            #pragma unroll
            for (int ks = 0; ks < 2; ++ks) {
                bf16x8 af[4], bf[4];
                #pragma unroll
                for (int m = 0; m < 4; ++m) {
                    const int row = (wr << 6) + (m << 4) + (lane & 15);
                    const int corig = (ks << 2) + (lane >> 4);
                    af[m] = *(const bf16x8*)((const char*)Ac +
                            (row << 7) + ((corig ^ (row & 7)) << 4));
                }
                #pragma unroll
                for (int n = 0; n < 4; ++n) {
                    const int row = (wc << 6) + (n << 4) + (lane & 15);
                    const int corig = (ks << 2) + (lane >> 4);
                    bf[n] = *(const bf16x8*)((const char*)Bc +
                            (row << 7) + ((corig ^ (row & 7)) << 4));
                }
                #pragma unroll
                for (int m = 0; m < 4; ++m)
                    #pragma unroll
                    for (int n = 0; n < 4; ++n)
                        acc[m][n] = __builtin_amdgcn_mfma_f32_16x16x32_bf16(
                            af[m], bf[n], acc[m][n], 0, 0, 0);
            }
            __syncthreads();   // all waves done reading buf[par]; next staging may overwrite
        }

        // ---- drain: 4 rounds of 32 cols; cv/ci alias A buffers (no loads pending) ----
        #pragma unroll
        for (int rnd = 0; rnd < 4; ++rnd) {
            const int wcr = rnd >> 1;
            const int nf0 = (rnd & 1) << 1;
            if (wc == wcr) {
                #pragma unroll
                for (int m = 0; m < 4; ++m) {
                    #pragma unroll
                    for (int nn = 0; nn < 2; ++nn) {
                        #pragma unroll
                        for (int j = 0; j < 4; ++j) {
                            const int row = (wr << 6) + (m << 4) + ((lane >> 4) << 2) + j;
                            const float v = acc[m][nf0 + nn][j];
                            if (v >= thresh[row]) {   // cap 32 == round width: always safe
                                const int p = atomicAdd(&cnt[row], 1);
                                cv[(row << 5) + p] = v;
                                ci[(row << 5) + p] =
                                    (unsigned short)(c0 + (wcr << 6) + ((nf0 + nn) << 4) + (lane & 15));
                            }
                        }
                    }
                }
            }
            __syncthreads();
            if (tid < 256) {
                const int r = tid;
                const int n_ = cnt[r];
                float* tv = &topv[r * MCAND];
                unsigned short* ti = &topi[r * MCAND];
                for (int q = 0; q < n_; ++q) {
                    const float v = cv[(r << 5) + q];
                    const unsigned short c = ci[(r << 5) + q];
                    if (v > tv[MCAND-1] || (v == tv[MCAND-1] && c < ti[MCAND-1])) {
                        int p = MCAND - 1;
                        while (p > 0 && (v > tv[p-1] || (v == tv[p-1] && c < ti[p-1]))) {
                            tv[p] = tv[p-1]; ti[p] = ti[p-1]; --p;
                        }
                        tv[p] = v; ti[p] = c;
                    }
                }
                cnt[r] = 0;
                thresh[r] = tv[MCAND-1];
            }
            __syncthreads();
        }
    }
#undef STAGE_STEP

    if (tid < 256) {
        const size_t base = (((size_t)s * 64 + mblk) * 256 + tid) * MCAND;
        #pragma unroll
        for (int j = 0; j < MCAND; ++j) {
            pv[base + j] = topv[tid * MCAND + j];
            pi[base + j] = topi[tid * MCAND + j];
        }
    }
}

// ------------- K3: wave bitonic top-16-of-64 by filter value, fp64 rescore, scatter -------------
__global__ __launch_bounds__(256) void k_rescore(
    const float* __restrict__ t, const float* __restrict__ pv,
    const unsigned short* __restrict__ pi, float* __restrict__ out)
{
    const int wave = threadIdx.x >> 6;
    const int lane = threadIdx.x & 63;
    const int r = blockIdx.x * 4 + wave;
    const int mblk = r >> 8, local = r & 255;

    // lane q holds candidate (split q>>4, slot q&15)
    const int sp = lane >> 4, slot = lane & 15;
    const size_t cbase = (((size_t)sp * 64 + mblk) * 256 + local) * MCAND;
    const float v = pv[cbase + slot];
    const unsigned int idxc = pi[cbase + slot];
    // monotone key: v desc, idx asc. empty slots (v=-1e30, idx=0xFFFF) sort last.
    const unsigned int u = __float_as_uint(v);
    const unsigned int mkey = (u & 0x80000000u) ? ~u : (u | 0x80000000u);
    unsigned long long key = ((unsigned long long)mkey << 16) |
                             (unsigned long long)((~idxc) & 0xFFFFu);

    // 64-lane bitonic sort, descending
    #pragma unroll
    for (int k = 2; k <= 64; k <<= 1) {
        #pragma unroll
        for (int j = k >> 1; j > 0; j >>= 1) {
            const unsigned long long other = __shfl_xor(key, j, 64);
            const bool lower = (lane & j) == 0;
            const bool ascBlock = (lane & k) == 0;
            const bool takeMax = (lower == ascBlock);
            const bool mineBigger = key > other;
            key = (takeMax == mineBigger) ? key : other;
        }
    }
    const int cid = (int)((~(unsigned int)key) & 0xFFFFu);  // lanes 0..15: top-16 cand columns

    const float4 a0 = *(const float4*)&t[(size_t)r * DD + lane * 8];
    const float4 a1 = *(const float4*)&t[(size_t)r * DD + lane * 8 + 4];

    double bestv[KSEL];
    int    besti[KSEL];
    #pragma unroll
    for (int j = 0; j < KSEL; ++j) { bestv[j] = -1e300; besti[j] = 0x7fffffff; }

    for (int q = 0; q < RESCORE; ++q) {
        const int c = __shfl(cid, q, 64);
        const float4 v0 = *(const float4*)&t[(size_t)c * DD + lane * 8];
        const float4 v1 = *(const float4*)&t[(size_t)c * DD + lane * 8 + 4];
        double sdot = 0.0;
        sdot += (double)a0.x * (double)v0.x;
        sdot += (double)a0.y * (double)v0.y;
        sdot += (double)a0.z * (double)v0.z;
        sdot += (double)a0.w * (double)v0.w;
        sdot += (double)a1.x * (double)v1.x;
        sdot += (double)a1.y * (double)v1.y;
        sdot += (double)a1.z * (double)v1.z;
        sdot += (double)a1.w * (double)v1.w;
        #pragma unroll
        for (int off = 32; off > 0; off >>= 1)
            sdot += __shfl_down(sdot, off, 64);
        if (lane == 0) {
            if (sdot > bestv[KSEL-1] || (sdot == bestv[KSEL-1] && c < besti[KSEL-1])) {
                int p = KSEL - 1;
                while (p > 0 && (sdot > bestv[p-1] ||
                                 (sdot == bestv[p-1] && c < besti[p-1]))) {
                    bestv[p] = bestv[p-1]; besti[p] = besti[p-1]; --p;
                }
                bestv[p] = sdot; besti[p] = c;
            }
        }
    }

    if (lane == 0) {
        #pragma unroll
        for (int j = 0; j < KSEL; ++j)
            out[(size_t)besti[j] * NN + r] = 1.0f;
    }
}

extern "C" void kernel_launch(void* const* d_in, const int* in_sizes, int n_in,
                              void* d_out, int out_size, void* d_ws, size_t ws_size,
                              hipStream_t stream) {
    const int*   idx  = (const int*)d_in[0];
    const float* emb  = (const float*)d_in[1];
    const float* linw = (const float*)d_in[2];
    const float* linb = (const float*)d_in[3];
    float* out = (float*)d_out;

    // ws: t f32 32MB @0; tb bf16 16MB @32M; pv f32 4MB @48M; pi u16 2MB @52M
    float*          t  = (float*)d_ws;
    unsigned short* tb = (unsigned short*)((char*)d_ws + (size_t)32 * 1024 * 1024);
    float*          pv = (float*)((char*)d_ws + (size_t)48 * 1024 * 1024);
    unsigned short* pi = (unsigned short*)((char*)d_ws + (size_t)52 * 1024 * 1024);

    (void)hipMemsetAsync(d_out, 0, (size_t)NN * (size_t)NN * sizeof(float), stream);

    k_transform<<<dim3(256 * 8), dim3(256), 0, stream>>>(idx, emb, linw, linb, t, tb);
    k_sim_topk<<<dim3(256), dim3(512), 0, stream>>>(tb, pv, pi);
    k_rescore<<<dim3(NN / 4), dim3(256), 0, stream>>>(t, pv, pi, out);
}

// Round 8
// 2321.078 us; speedup vs baseline: 1.3753x; 1.0075x over previous
//
#include <hip/hip_runtime.h>
#include <hip/hip_bf16.h>
#include <math.h>

#define NN 16384
#define DD 512
#define KSEL 10
#define MCAND 16   // filter keeps top-16 per column-split
#define NSPLIT 4   // column splits for k_sim_topk
#define RESCORE 16 // fp64-rescored candidates per row (top-16 of 64 by filter value)

typedef __bf16 bf16x8 __attribute__((ext_vector_type(8)));
typedef float  f32x4  __attribute__((ext_vector_type(4)));

#define GLOAD_LDS16(gsrc, ldst) \
    __builtin_amdgcn_global_load_lds( \
        (const __attribute__((address_space(1))) void*)(gsrc), \
        (__attribute__((address_space(3))) void*)(ldst), 16, 0, 0)

// ---------------- K1: t = tanh(3 * (emb[idx] @ W^T + b)); also emit bf16 copy ----------------
__global__ __launch_bounds__(256) void k_transform(
    const int* __restrict__ idx, const float* __restrict__ emb,
    const float* __restrict__ W, const float* __restrict__ bias,
    float* __restrict__ t_out, unsigned short* __restrict__ tb_out)
{
    __shared__ float As[32][68];   // [k][m]
    __shared__ float Bs[32][68];   // [k][n]
    const int tid = threadIdx.x;
    const int tx = tid & 15, ty = tid >> 4;
    const int m0 = (blockIdx.x >> 3) << 6;
    const int n0 = (blockIdx.x & 7) << 6;

    float acc[4][4] = {};

    const int f0 = tid, f1 = tid + 256;
    const int r0 = f0 >> 3, c0_ = f0 & 7;
    const int r1 = f1 >> 3, c1_ = f1 & 7;
    const int ga0 = idx[m0 + r0];
    const int ga1 = idx[m0 + r1];

    for (int kc = 0; kc < DD; kc += 32) {
        const float4 a0 = *(const float4*)&emb[(size_t)ga0 * DD + kc + (c0_ << 2)];
        const float4 a1 = *(const float4*)&emb[(size_t)ga1 * DD + kc + (c1_ << 2)];
        const float4 b0 = *(const float4*)&W[(size_t)(n0 + r0) * DD + kc + (c0_ << 2)];
        const float4 b1 = *(const float4*)&W[(size_t)(n0 + r1) * DD + kc + (c1_ << 2)];
        As[(c0_<<2)+0][r0] = a0.x; As[(c0_<<2)+1][r0] = a0.y;
        As[(c0_<<2)+2][r0] = a0.z; As[(c0_<<2)+3][r0] = a0.w;
        As[(c1_<<2)+0][r1] = a1.x; As[(c1_<<2)+1][r1] = a1.y;
        As[(c1_<<2)+2][r1] = a1.z; As[(c1_<<2)+3][r1] = a1.w;
        Bs[(c0_<<2)+0][r0] = b0.x; Bs[(c0_<<2)+1][r0] = b0.y;
        Bs[(c0_<<2)+2][r0] = b0.z; Bs[(c0_<<2)+3][r0] = b0.w;
        Bs[(c1_<<2)+0][r1] = b1.x; Bs[(c1_<<2)+1][r1] = b1.y;
        Bs[(c1_<<2)+2][r1] = b1.z; Bs[(c1_<<2)+3][r1] = b1.w;
        __syncthreads();
        #pragma unroll
        for (int k = 0; k < 32; ++k) {
            const float4 a = *(const float4*)&As[k][ty << 2];
            const float4 b = *(const float4*)&Bs[k][tx << 2];
            const float av[4] = {a.x, a.y, a.z, a.w};
            const float bv[4] = {b.x, b.y, b.z, b.w};
            #pragma unroll
            for (int i = 0; i < 4; ++i)
                #pragma unroll
                for (int j = 0; j < 4; ++j)
                    acc[i][j] = fmaf(av[i], bv[j], acc[i][j]);
        }
        __syncthreads();
    }

    #pragma unroll
    for (int i = 0; i < 4; ++i) {
        const int m = m0 + (ty << 2) + i;
        float o[4];
        union { __hip_bfloat16 h[4]; ushort4 u; } cc;
        #pragma unroll
        for (int j = 0; j < 4; ++j) {
            const int n = n0 + (tx << 2) + j;
            o[j] = tanhf(3.0f * (acc[i][j] + bias[n]));
            cc.h[j] = __float2bfloat16(o[j]);
        }
        *(float4*)&t_out[(size_t)m * DD + n0 + (tx << 2)] =
            make_float4(o[0], o[1], o[2], o[3]);
        *(ushort4*)&tb_out[(size_t)m * DD + n0 + (tx << 2)] = cc.u;
    }
}

// ------------- K2: bf16 MFMA sim filter — 256x128 tile, BK=32, 4-buffer ring, counted vmcnt -------------
// 512 threads (8 waves, 4x2 grid of 64x64 wave-tiles). Raw s_barrier + s_waitcnt vmcnt(3):
// loads stay 2 K-steps in flight across barriers (T3+T4). LDS: A ring 4x16KB @0,
// B ring 4x8KB @65536, aux @98304. Drain uses __syncthreads (vmcnt already 0);
// cv/ci (stride 33, conflict-free) alias ring memory after the post-loop barrier.
__global__ __launch_bounds__(512) void k_sim_topk(
    const unsigned short* __restrict__ tb,
    float* __restrict__ pv, unsigned short* __restrict__ pi)
{
    __shared__ __align__(16) char SM[124928];
    float*          topv   = (float*)(SM + 98304);            // [256][16]
    unsigned short* topi   = (unsigned short*)(SM + 114688);  // [256][16]
    float*          thresh = (float*)(SM + 122880);           // [256]
    int*            cnt    = (int*)(SM + 123904);             // [256]
    float*          cv     = (float*)(SM);                    // [256][33] alias rings
    int*            ci     = (int*)(SM + 36864);              // [256][33] alias rings

    const int tid  = threadIdx.x;
    const int wave = tid >> 6;     // 0..7
    const int lane = tid & 63;
    const int wr   = wave >> 1;    // 0..3 -> rows wr*64
    const int wc   = wave & 1;     // 0..1 -> cols wc*64

    // XCD-aware decode (perf-only): split s pinned to XCD pair; bijective mblk.
    const int bid  = blockIdx.x;
    const int s    = (bid & 7) >> 1;                 // 0..3
    const int mblk = ((bid & 1) << 5) | (bid >> 3);  // 0..63
    const int m0   = mblk << 8;                      // 256-row panel
    const int c_begin = s * (NN / NSPLIT);

    if (tid < 256) {
        thresh[tid] = -1e30f;
        cnt[tid] = 0;
        #pragma unroll
        for (int j = 0; j < MCAND; ++j) { topv[tid*MCAND + j] = -1e30f; topi[tid*MCAND + j] = 0xFFFFu; }
    }
    __syncthreads();

    const char* tbb = (const char*)tb;
    const int l4r = lane >> 2;   // row within 16-row staging group
    const int l4u = lane & 3;    // 16B unit within 64B row-chunk

    for (int ct = 0; ct < (NN / NSPLIT) / 128; ++ct) {
        const int c0 = c_begin + (ct << 7);
        f32x4 acc[4][4] = {};

        // stage K-step k into ring[k&3]: A rows m0..m0+255 (2 instr/wave), B rows c0..c0+127 (1)
        auto STAGE = [&](int k) {
            const int rb = k & 3;
            const size_t kb = (size_t)k << 6;   // 32 k * 2B
            char* Ad = SM + (rb << 14);
            char* Bd = SM + 65536 + (rb << 13);
            #pragma unroll
            for (int i_ = 0; i_ < 2; ++i_) {
                const int rl = (wave << 5) + (i_ << 4) + l4r;          // local A row
                GLOAD_LDS16(tbb + (size_t)(m0 + rl) * 1024 + kb + ((size_t)(l4u ^ ((rl >> 1) & 3)) << 4),
                            Ad + (wave << 11) + (i_ << 10));
            }
            {
                const int rl = (wave << 4) + l4r;                      // local B row
                GLOAD_LDS16(tbb + (size_t)(c0 + rl) * 1024 + kb + ((size_t)(l4u ^ ((rl >> 1) & 3)) << 4),
                            Bd + (wave << 10));
            }
        };

        auto COMPUTE = [&](int k) {
            const int rb = k & 3;
            const char* Ac = SM + (rb << 14);
            const char* Bc = SM + 65536 + (rb << 13);
            const int u = lane >> 4;
            bf16x8 af[4], bf[4];
            #pragma unroll
            for (int m = 0; m < 4; ++m) {
                const int row = (wr << 6) + (m << 4) + (lane & 15);
                af[m] = *(const bf16x8*)(Ac + (row << 6) + ((u ^ ((row >> 1) & 3)) << 4));
            }
            #pragma unroll
            for (int n = 0; n < 4; ++n) {
                const int row = (wc << 6) + (n << 4) + (lane & 15);
                bf[n] = *(const bf16x8*)(Bc + (row << 6) + ((u ^ ((row >> 1) & 3)) << 4));
            }
            #pragma unroll
            for (int m = 0; m < 4; ++m)
                #pragma unroll
                for (int n = 0; n < 4; ++n)
                    acc[m][n] = __builtin_amdgcn_mfma_f32_16x16x32_bf16(
                        af[m], bf[n], acc[m][n], 0, 0, 0);
        };

        // prologue: steps 0,1 in flight
        STAGE(0); STAGE(1);
        // steady state: wait own stage(k) done (3 newest may fly), barrier, prefetch k+2
        for (int kc = 0; kc < 14; ++kc) {
            asm volatile("s_waitcnt vmcnt(3)" ::: "memory");
            __builtin_amdgcn_s_barrier();
            STAGE(kc + 2);
            COMPUTE(kc);
        }
        asm volatile("s_waitcnt vmcnt(3)" ::: "memory");
        __builtin_amdgcn_s_barrier();
        COMPUTE(14);
        asm volatile("s_waitcnt vmcnt(0)" ::: "memory");
        __builtin_amdgcn_s_barrier();
        COMPUTE(15);

        __syncthreads();   // all waves done reading rings before cv/ci alias-writes

        // ---- drain: 4 rounds of 32 cols; stride-33 cv/ci (bank-spread) ----
        #pragma unroll
        for (int rnd = 0; rnd < 4; ++rnd) {
            const int wcr = rnd >> 1;
            const int nf0 = (rnd & 1) << 1;
            if (wc == wcr) {
                #pragma unroll
                for (int m = 0; m < 4; ++m) {
                    #pragma unroll
                    for (int nn = 0; nn < 2; ++nn) {
                        #pragma unroll
                        for (int j = 0; j < 4; ++j) {
                            const int row = (wr << 6) + (m << 4) + ((lane >> 4) << 2) + j;
                            const float v = acc[m][nf0 + nn][j];
                            if (v >= thresh[row]) {   // cap 32 == round width: always safe
                                const int p = atomicAdd(&cnt[row], 1);
                                cv[row * 33 + p] = v;
                                ci[row * 33 + p] = c0 + (wcr << 6) + ((nf0 + nn) << 4) + (lane & 15);
                            }
                        }
                    }
                }
            }
            __syncthreads();
            if (tid < 256) {
                const int r = tid;
                const int n_ = cnt[r];
                float* tv = &topv[r * MCAND];
                unsigned short* ti = &topi[r * MCAND];
                for (int q = 0; q < n_; ++q) {
                    const float v = cv[r * 33 + q];
                    const unsigned short c = (unsigned short)ci[r * 33 + q];
                    if (v > tv[MCAND-1] || (v == tv[MCAND-1] && c < ti[MCAND-1])) {
                        int p = MCAND - 1;
                        while (p > 0 && (v > tv[p-1] || (v == tv[p-1] && c < ti[p-1]))) {
                            tv[p] = tv[p-1]; ti[p] = ti[p-1]; --p;
                        }
                        tv[p] = v; ti[p] = c;
                    }
                }
                cnt[r] = 0;
                thresh[r] = tv[MCAND-1];
            }
            __syncthreads();
        }
    }

    if (tid < 256) {
        const size_t base = (((size_t)s * 64 + mblk) * 256 + tid) * MCAND;
        #pragma unroll
        for (int j = 0; j < MCAND; ++j) {
            pv[base + j] = topv[tid * MCAND + j];
            pi[base + j] = topi[tid * MCAND + j];
        }
    }
}

// ------------- K3: wave bitonic top-16-of-64 by filter value, fp64 rescore, scatter -------------
__global__ __launch_bounds__(256) void k_rescore(
    const float* __restrict__ t, const float* __restrict__ pv,
    const unsigned short* __restrict__ pi, float* __restrict__ out)
{
    const int wave = threadIdx.x >> 6;
    const int lane = threadIdx.x & 63;
    const int r = blockIdx.x * 4 + wave;
    const int mblk = r >> 8, local = r & 255;

    // lane q holds candidate (split q>>4, slot q&15)
    const int sp = lane >> 4, slot = lane & 15;
    const size_t cbase = (((size_t)sp * 64 + mblk) * 256 + local) * MCAND;
    const float v = pv[cbase + slot];
    const unsigned int idxc = pi[cbase + slot];
    // monotone key: v desc, idx asc. empty slots (v=-1e30, idx=0xFFFF) sort last.
    const unsigned int u = __float_as_uint(v);
    const unsigned int mkey = (u & 0x80000000u) ? ~u : (u | 0x80000000u);
    unsigned long long key = ((unsigned long long)mkey << 16) |
                             (unsigned long long)((~idxc) & 0xFFFFu);

    // 64-lane bitonic sort, descending
    #pragma unroll
    for (int k = 2; k <= 64; k <<= 1) {
        #pragma unroll
        for (int j = k >> 1; j > 0; j >>= 1) {
            const unsigned long long other = __shfl_xor(key, j, 64);
            const bool lower = (lane & j) == 0;
            const bool ascBlock = (lane & k) == 0;
            const bool takeMax = (lower == ascBlock);
            const bool mineBigger = key > other;
            key = (takeMax == mineBigger) ? key : other;
        }
    }
    const int cid = (int)((~(unsigned int)key) & 0xFFFFu);  // lanes 0..15: top-16 cand columns

    const float4 a0 = *(const float4*)&t[(size_t)r * DD + lane * 8];
    const float4 a1 = *(const float4*)&t[(size_t)r * DD + lane * 8 + 4];

    double bestv[KSEL];
    int    besti[KSEL];
    #pragma unroll
    for (int j = 0; j < KSEL; ++j) { bestv[j] = -1e300; besti[j] = 0x7fffffff; }

    for (int q = 0; q < RESCORE; ++q) {
        const int c = __shfl(cid, q, 64);
        const float4 v0 = *(const float4*)&t[(size_t)c * DD + lane * 8];
        const float4 v1 = *(const float4*)&t[(size_t)c * DD + lane * 8 + 4];
        double sdot = 0.0;
        sdot += (double)a0.x * (double)v0.x;
        sdot += (double)a0.y * (double)v0.y;
        sdot += (double)a0.z * (double)v0.z;
        sdot += (double)a0.w * (double)v0.w;
        sdot += (double)a1.x * (double)v1.x;
        sdot += (double)a1.y * (double)v1.y;
        sdot += (double)a1.z * (double)v1.z;
        sdot += (double)a1.w * (double)v1.w;
        #pragma unroll
        for (int off = 32; off > 0; off >>= 1)
            sdot += __shfl_down(sdot, off, 64);
        if (lane == 0) {
            if (sdot > bestv[KSEL-1] || (sdot == bestv[KSEL-1] && c < besti[KSEL-1])) {
                int p = KSEL - 1;
                while (p > 0 && (sdot > bestv[p-1] ||
                                 (sdot == bestv[p-1] && c < besti[p-1]))) {
                    bestv[p] = bestv[p-1]; besti[p] = besti[p-1]; --p;
                }
                bestv[p] = sdot; besti[p] = c;
            }
        }
    }

    if (lane == 0) {
        #pragma unroll
        for (int j = 0; j < KSEL; ++j)
            out[(size_t)besti[j] * NN + r] = 1.0f;
    }
}

extern "C" void kernel_launch(void* const* d_in, const int* in_sizes, int n_in,
                              void* d_out, int out_size, void* d_ws, size_t ws_size,
                              hipStream_t stream) {
    const int*   idx  = (const int*)d_in[0];
    const float* emb  = (const float*)d_in[1];
    const float* linw = (const float*)d_in[2];
    const float* linb = (const float*)d_in[3];
    float* out = (float*)d_out;

    // ws: t f32 32MB @0; tb bf16 16MB @32M; pv f32 4MB @48M; pi u16 2MB @52M
    float*          t  = (float*)d_ws;
    unsigned short* tb = (unsigned short*)((char*)d_ws + (size_t)32 * 1024 * 1024);
    float*          pv = (float*)((char*)d_ws + (size_t)48 * 1024 * 1024);
    unsigned short* pi = (unsigned short*)((char*)d_ws + (size_t)52 * 1024 * 1024);

    (void)hipMemsetAsync(d_out, 0, (size_t)NN * (size_t)NN * sizeof(float), stream);

    k_transform<<<dim3(256 * 8), dim3(256), 0, stream>>>(idx, emb, linw, linb, t, tb);
    k_sim_topk<<<dim3(256), dim3(512), 0, stream>>>(tb, pv, pi);
    k_rescore<<<dim3(NN / 4), dim3(256), 0, stream>>>(t, pv, pi, out);
}